// Round 8
// baseline (768.964 us; speedup 1.0000x reference)
//
#include <hip/hip_runtime.h>
#include <math.h>

#define BS 512
#define NN 256
#define RB 16
#define OMEGA_F 1.5f

// ---------------------------------------------------------------------------
// Round-13: sor_gmat rewrite -- X to LDS, A to the scalar path.
//
// Round-12 evidence: LDS-GEMM == global-GEMM (447 vs 455 us) at VALUBusy
// 26->44%. Diagnosis: the A-tile is wave-uniform-broadcast ~120x b128 per
// wave per KB-step; per CU = 960 reads/step ~ 11.5K cyc on the LDS pipe
// (or the same volume on VMEM in r11) -- the tile is re-read once PER WAVE
// through a throughput pipe, 8x redundancy. Also: occupancy == one block's
// waves in EVERY round -> 1 WG/CU is law on this setup; co-residency is
// not coming.
//
// Fix (this round):
//  (1) X lives in LDS (Xl[256][128] = 128 KB -- the panel fits). Solve
//      writes X directly to LDS; GEMM reads X[j][tc] per-lane (conflict-
//      free b32), only ~16 reads per active j-block per wave, shared
//      across 16 fmacs via xv[16] registers. LDS pipe load drops ~8x.
//  (2) A-tile rows are read as wave-UNIFORM float4 loads (r0,j0,rr all
//      uniform; qU readfirstlane'd; no global stores in the loop; const
//      __restrict__) -> SMRD s_load path through K$/L2, feeding
//      v_fmac(acc, s_av, v_xv) with one SGPR operand per fmac. Even the
//      VMEM-broadcast fallback matches r11's path, so downside ~ 0.
//  (3) Register demand ~50 (acc[16]+xv[16]+temps) -- far under the
//      immovable 128 budget; no spill possible. Partials combine via a
//      2-stage LDS tree (q2->buf0, q3->buf1; then q0+=buf0, q1+=buf1 and
//      rewrites buf1; then q0 += buf1). 16x16 diag tile (1 KB) serves the
//      solve's uniform reads; 8 KB ldsA panel serves per-lane a_rt.
//      Total LDS 153 KB (1 WG/CU anyway). No swizzle: the only conflicted
//      access left is the ONE-TIME epilogue transpose read (~1K cyc).
//
// Kernel B (sor_iter) unchanged from round-12 (validated).
// ---------------------------------------------------------------------------

__global__ __launch_bounds__(512)
void sor_gmat(const float* __restrict__ A, float* __restrict__ gws)
{
    const int bp  = blockIdx.x;
    const int b   = bp >> 1;
    const int p   = bp & 1;                      // column panel [128p, 128p+128)
    const int tid = threadIdx.x;
    const int tc  = tid & 127;                   // local column
    const int t   = 128 * p + tc;                // global column
    const int q   = tid >> 7;                    // 0..3 j-quarter
    const int qU  = __builtin_amdgcn_readfirstlane(q);
    const float* __restrict__ Ab = A + (size_t)b * NN * NN;

    // 153 KB: Xl 128K | ldsA 8K | ldsD 1K | acc2 16K
    __shared__ __align__(16) char smem[156672];
    float* Xl              = (float*)smem;                        // X[256][128]
    float (*ldsA)[128]     = (float (*)[128])(smem + 131072);     // A panel rows x 128 cols
    float (*ldsD)[16]      = (float (*)[16])(smem + 139264);      // 16x16 diag tile
    float (*acc2)[RB][128] = (float (*)[RB][128])(smem + 140288); // 2 combine bufs

    for (int KB = 0; KB < NN / RB; ++KB) {
        const int r0 = KB * RB;
        __syncthreads();                         // prev step's ldsA/ldsD/Xl readers done
        // stage ldsA rows [r0,r0+16) x cols [128p,128p+128): 1 float4/thread
        {
            const int rr = tid >> 5, c4 = (tid & 31) << 2;
            *(float4*)&ldsA[rr][c4] = *(const float4*)&Ab[(size_t)(r0 + rr) * NN + 128 * p + c4];
        }
        // stage 16x16 diag tile: threads 0..63
        if (tid < 64) {
            const int rr = tid >> 2, c4 = (tid & 3) << 2;
            *(float4*)&ldsD[rr][c4] = *(const float4*)&Ab[(size_t)(r0 + rr) * NN + r0 + c4];
        }
        __syncthreads();

        // trailing partial: acc[rr] = sum over owned j-blocks (<r0) of
        //   A[r0+rr][j] * X[j][t];  A uniform (SMRD), X per-lane from LDS.
        float acc[RB];
        #pragma unroll
        for (int rr = 0; rr < RB; ++rr) acc[rr] = 0.f;
        #pragma unroll
        for (int m = 0; m < 4; ++m) {
            const int kb = 4 * m + qU;
            if (kb < KB) {                       // wave-uniform branch
                const int j0 = kb * RB;
                float xv[RB];
                #pragma unroll
                for (int jj = 0; jj < RB; ++jj)
                    xv[jj] = Xl[(j0 + jj) * 128 + tc];
                #pragma unroll
                for (int rr = 0; rr < RB; ++rr) {
                    #pragma unroll
                    for (int j4 = 0; j4 < 4; ++j4) {
                        const float4 av = *(const float4*)&Ab[(size_t)(r0 + rr) * NN + j0 + 4 * j4];
                        acc[rr] += av.x * xv[4 * j4 + 0] + av.y * xv[4 * j4 + 1]
                                 + av.z * xv[4 * j4 + 2] + av.w * xv[4 * j4 + 3];
                    }
                }
            }
        }
        // 2-stage combine tree: q2->buf0, q3->buf1
        if (q >= 2) {
            #pragma unroll
            for (int rr = 0; rr < RB; ++rr) acc2[q - 2][rr][tc] = acc[rr];
        }
        __syncthreads();
        if (q == 1) {                            // q1 += buf1(q3), rewrite buf1
            #pragma unroll
            for (int rr = 0; rr < RB; ++rr) {
                acc[rr] += acc2[1][rr][tc];      // read-before-write, same thread/addr
                acc2[1][rr][tc] = acc[rr];
            }
        }
        if (q == 0) {                            // q0 += buf0(q2)
            #pragma unroll
            for (int rr = 0; rr < RB; ++rr) acc[rr] += acc2[0][rr][tc];
        }
        __syncthreads();
        // serial 16-row solve on the q==0 threads (one chain per column)
        if (q == 0) {
            float s_[RB];
            #pragma unroll
            for (int rr = 0; rr < RB; ++rr) s_[rr] = acc[rr] + acc2[1][rr][tc];
            #pragma unroll
            for (int rr = 0; rr < RB; ++rr) {
                const int r = r0 + rr;
                const float a_rt = ldsA[rr][tc];
                const float brt  = (t > r) ? (-OMEGA_F) * a_rt
                                 : ((t == r) ? (1.0f - OMEGA_F) * a_rt : 0.0f);
                const float diag = ldsD[rr][rr];           // uniform broadcast
                const float val  = (brt - OMEGA_F * s_[rr]) / diag;
                Xl[r * 128 + tc] = val;                    // X row -> LDS (conflict-free)
                #pragma unroll
                for (int rr2 = rr + 1; rr2 < RB; ++rr2)
                    s_[rr2] += ldsD[rr2][rr] * val;        // uniform broadcast
            }
        }
    }
    __syncthreads();                             // all X written

    // ---- epilogue: store G in phase-2 order (coalesced float4 stores) ----
    // Read Xl[row][cl..cl+3] (row per-lane -> same-bank b128, ~16x aliased,
    // but executed ONCE: ~1K cyc, negligible). Store: lanes consecutive ->
    // consecutive global addresses.
    const int u8 = tid & 63, wl = tid >> 6;
    float* __restrict__ gb = gws + (size_t)b * (NN * NN);
    #pragma unroll
    for (int rg = 0; rg < 4; ++rg) {
        const int row = 64 * rg + u8;
        #pragma unroll
        for (int k = 0; k < 4; ++k) {
            const int cl = 16 * wl + 4 * k;      // local col of first elem
            const float4 v = *(const float4*)&Xl[row * 128 + cl];
            *(float4*)&gb[((size_t)((rg * 4 + k) * 16 + 8 * p + wl)) * 256 + 4 * u8] = v;
        }
    }
}

__global__ __launch_bounds__(1024)
void sor_iter(const float* __restrict__ gws,
              const float* __restrict__ xs,
              const float* __restrict__ x0,
              const float* __restrict__ rtol,
              const int* __restrict__ maxiter_p,
              float* __restrict__ out)
{
    const int b   = blockIdx.x;
    const int tid = threadIdx.x;
    const int w   = __builtin_amdgcn_readfirstlane(tid >> 6);  // wave id 0..15
    const int u   = tid & 63;                                  // lane id

    __shared__ __align__(16) char smem[148544];
    float* gl            = (float*)smem;                       // 128 KB: G rows 128..255, phase-2 order
    float* e             = (float*)(smem + 131072);            // e[256], 1 KB
    float (*pbuf)[4][64] = (float (*)[4][64])(smem + 132096);  // 16 KB partials
    float* nrm           = (float*)(smem + 148480);            // 4 norms
    float* rs            = (float*)(smem + 148496);            // 8 reduce slots

    const int mi = *maxiter_p;
    float* __restrict__ outb = out + (size_t)b * (mi + 1);
    const float* __restrict__ gb = gws + (size_t)b * (NN * NN);

    // ---- prologue: e0, err0 = ||xs-x0||, xtol = ||xs||*rtol ----
    if (tid < NN) {
        const float xsv = xs[b * NN + tid];
        const float ev  = xsv - x0[b * NN + tid];
        e[tid] = ev;
        float s1 = ev * ev, s2 = xsv * xsv;
        #pragma unroll
        for (int off = 32; off > 0; off >>= 1) {
            s1 += __shfl_down(s1, off);
            s2 += __shfl_down(s2, off);
        }
        if (u == 0) { rs[tid >> 6] = s1; rs[4 + (tid >> 6)] = s2; }
    }

    // ---- load G: rows 0..127 -> registers, rows 128..255 -> LDS ----
    // (both fully coalesced: sor_gmat wrote phase-2 order)
    float4 gi[2][4];                             // 32 VGPRs
    #pragma unroll
    for (int rg = 0; rg < 2; ++rg)
        #pragma unroll
        for (int k = 0; k < 4; ++k)
            gi[rg][k] = *(const float4*)&gb[(size_t)((rg * 4 + k) * 16 + w) * 256 + 4 * u];
    #pragma unroll
    for (int rg = 0; rg < 2; ++rg)
        #pragma unroll
        for (int k = 0; k < 4; ++k) {
            const float4 v = *(const float4*)&gb[(size_t)(((rg + 2) * 4 + k) * 16 + w) * 256 + 4 * u];
            *(float4*)&gl[((rg * 4 + k) * 16 + w) * 256 + 4 * u] = v;
        }
    __syncthreads();
    const float err0 = sqrtf(rs[0] + rs[1] + rs[2] + rs[3]);
    const float xtol = sqrtf(rs[4] + rs[5] + rs[6] + rs[7]) * rtol[b];
    if (tid == 0) outb[0] = err0;

    // ---- iterate: e <- G e, err history, per-batch early exit ----
    const float4* __restrict__ e4 = (const float4*)e;
    float err = err0;
    int s = 1;
    for (; s <= mi; ++s) {
        if (!(err > xtol)) break;                // block-uniform
        float a0 = 0.f, a1 = 0.f, a2 = 0.f, a3 = 0.f;
        #pragma unroll
        for (int k = 0; k < 4; ++k) {
            const float4 ev4 = e4[4 * w + k];    // wave-uniform broadcast
            const float4 v2 = *(const float4*)&gl[(k * 16 + w) * 256 + 4 * u];        // row 128+u
            const float4 v3 = *(const float4*)&gl[((4 + k) * 16 + w) * 256 + 4 * u];  // row 192+u
            a0 += gi[0][k].x*ev4.x + gi[0][k].y*ev4.y + gi[0][k].z*ev4.z + gi[0][k].w*ev4.w;
            a1 += gi[1][k].x*ev4.x + gi[1][k].y*ev4.y + gi[1][k].z*ev4.z + gi[1][k].w*ev4.w;
            a2 += v2.x*ev4.x + v2.y*ev4.y + v2.z*ev4.z + v2.w*ev4.w;
            a3 += v3.x*ev4.x + v3.y*ev4.y + v3.z*ev4.z + v3.w*ev4.w;
        }
        pbuf[w][0][u] = a0;                      // lanes -> consecutive banks
        pbuf[w][1][u] = a1;
        pbuf[w][2][u] = a2;
        pbuf[w][3][u] = a3;
        __syncthreads();
        if (tid < NN) {                          // row r = tid
            const int kk = tid >> 6, uu = tid & 63;
            float sum = 0.f;
            #pragma unroll
            for (int w2 = 0; w2 < 16; ++w2) sum += pbuf[w2][kk][uu];
            e[tid] = sum;                        // e <- G e
            float loc = sum * sum;
            #pragma unroll
            for (int off = 32; off > 0; off >>= 1) loc += __shfl_down(loc, off);
            if (uu == 0) nrm[kk] = loc;
        }
        __syncthreads();
        err = sqrtf(nrm[0] + nrm[1] + nrm[2] + nrm[3]);
        if (tid == 0) outb[s] = err;
    }
    // zero-fill the unwritten tail
    for (int idx = s + tid; idx <= mi; idx += 1024) outb[idx] = 0.f;
}

extern "C" void kernel_launch(void* const* d_in, const int* in_sizes, int n_in,
                              void* d_out, int out_size, void* d_ws, size_t ws_size,
                              hipStream_t stream) {
    const float* A     = (const float*)d_in[0];
    // d_in[1] = b: unused (error iteration e_{k+1} = G e_k needs no affine term)
    const float* xs    = (const float*)d_in[2];
    const float* theta = (const float*)d_in[3];
    const float* rtol  = (const float*)d_in[4];
    const int*   mi    = (const int*)d_in[5];
    float* out = (float*)d_out;
    float* gws = (float*)d_ws;                   // needs 512*256*256*4 = 128 MB

    // kernel A: compute G, write to workspace in phase-2 layout (streamed)
    sor_gmat<<<dim3(BS * 2), dim3(512), 0, stream>>>(A, gws);
    // kernel B: load G (regs + LDS), iterate e <- G e with zero spill
    sor_iter<<<dim3(BS), dim3(1024), 0, stream>>>(gws, xs, theta, rtol, mi, out);
}